// Round 16
// baseline (229.068 us; speedup 1.0000x reference)
//
#include <hip/hip_runtime.h>
#include <math.h>

// CapsLayer dynamic routing, MI355X fp32.
// x: [64, 2048, 8]  W: [2048, 32, 8, 16]  out: [64, 32, 16]
// Never materialize u_hat (256 MB); recompute per routing pass.
// R18: single-dispatch pass 0. Pass 0 is a pure GEMM (no softmax, no per-i
// coupling) -> a block owning FULL K can squash in-kernel and emit v0
// directly: route0d (256 blocks x 512 thr = 16 kslices x 8 b x 4 eq; each
// thread = route1's u-compute accumulated over its 128 i's; LDS combine
// over kslices; x1/32; in-wave squash; write v0). Kills route0 (~30us) +
// reduce_sq0 (~11us) + one gap. XCD locality: the 8 bc-siblings of capsule
// n share blk%8=n%8 -> same XCD; per-XCD W set = 4 caps x 1 MB = 4 MB = L2.
// route1 = R13/R17's proven 43.7us body (vin-reading, de-phased). reduce_sq
// = R16's fused reduce+squash(+addsrc). 5 dispatches total.
// Spill law (R3/R4/R6/R8/R16): no W batching across ii; #pragma unroll 1
// on every i-loop is load-bearing; route bodies max ~60 live VGPRs.
// Tripwires: route0d <= 35us (else revert R17 chain), route1 <= 47us,
// FETCH <= 80 MB per route kernel, absmax 0.00098.

#define B_TOT 64
#define I_TOT 2048
#define D_IN  8
#define NC    32
#define EV    16
#define OD    (NC*EV)      // 512 outputs per b
#define BC    8            // batch rows per block (softmax passes)
#define NBC   (B_TOT/BC)   // 8 b-chunks
#define ICH   8            // i's per block
#define NIC   (I_TOT/ICH)  // 256 i-chunks
#define S_ELEMS (B_TOT*OD) // 32768 floats = 128 KB per v-slice

__device__ __forceinline__ void fma4(float4& acc, float a, const float4& w) {
    acc.x = fmaf(a, w.x, acc.x);
    acc.y = fmaf(a, w.y, acc.y);
    acc.z = fmaf(a, w.z, acc.z);
    acc.w = fmaf(a, w.w, acc.w);
}

// ---- pass 0, single dispatch: v0 = squash((1/32) sum_i x[b,i,:] @ W[i]).
// Grid 256 = 8 bc x 32 n (blk%8 = n%8: the 8 bc-siblings of a capsule share
// one XCD's L2; W slice/XCD = 4 MB = L2). 512 thr = ks(16) x b(8) x eq(4).
// Thread: one float4 of s0 over its 128-i slice; LDS combine over ks;
// squash in wave 0; write v0 directly.
__global__ __launch_bounds__(512)
void route0d(const float* __restrict__ x, const float* __restrict__ W,
             float* __restrict__ v0)
{
    __shared__ __align__(16) float4 red[512];   // 8 KB

    const int t  = threadIdx.x;
    const int n  = blockIdx.x & 31;          // capsule
    const int bc = blockIdx.x >> 5;          // 0..7
    const int b0 = bc * 8;
    const int eq = t & 3;
    const int b  = (t >> 2) & 7;
    const int ks = t >> 5;                   // k-slice 0..15

    const float* Wn = W + n * 128 + eq * 4;
    const float* xb = x + (size_t)(b0 + b) * I_TOT * D_IN;

    float4 acc = make_float4(0.f, 0.f, 0.f, 0.f);
    const int iA = ks * 128;

    // unroll 1 is load-bearing (spill law): keeps 8 W float4 + 2 x float4
    // per iteration, ~55 live VGPRs.
    #pragma unroll 1
    for (int io = 0; io < 128; ++io) {
        const size_t i = (size_t)(iA + io);
        float4 wr[8];
        #pragma unroll
        for (int d = 0; d < 8; ++d)
            wr[d] = *(const float4*)&Wn[i * 4096 + d * 16];
        float4 xa = *(const float4*)&xb[i * 8];
        float4 xc = *(const float4*)&xb[i * 8 + 4];
        fma4(acc, xa.x, wr[0]); fma4(acc, xa.y, wr[1]);
        fma4(acc, xa.z, wr[2]); fma4(acc, xa.w, wr[3]);
        fma4(acc, xc.x, wr[4]); fma4(acc, xc.y, wr[5]);
        fma4(acc, xc.z, wr[6]); fma4(acc, xc.w, wr[7]);
    }
    red[t] = acc;
    __syncthreads();

    if (t < 32) {               // lanes (b,eq) of wave 0
        float4 s = red[t];
        #pragma unroll
        for (int j = 1; j < 16; ++j) {
            float4 r = red[t + j * 32];
            s.x += r.x; s.y += r.y; s.z += r.z; s.w += r.w;
        }
        const float pre = 1.0f / 32.0f;
        s.x *= pre; s.y *= pre; s.z *= pre; s.w *= pre;
        // squash: norm over 16 e = in-thread dot + shfl over the 2 eq bits
        float q2 = s.x*s.x + s.y*s.y + s.z*s.z + s.w*s.w;
        q2 += __shfl_xor(q2, 1, 64);
        q2 += __shfl_xor(q2, 2, 64);
        float sc = q2 / ((1.0f + q2) * sqrtf(q2));
        s.x *= sc; s.y *= sc; s.z *= sc; s.w *= sc;
        *(float4*)&v0[(size_t)(b0 + b) * OD + n * EV + eq * 4] = s;
    }
}

// ---- passes 1/2: c = softmax_n(u . vin). R13/R17's proven 43.7us body
// (vin materialized, read once into vr[4]) + R15 sibling de-phase.
// (iter 2 uses vin = v0+v1: dot is linear, so no logit carry needed)
__global__ __launch_bounds__(256, 4)
void route1(const float* __restrict__ x, const float* __restrict__ W,
            float* __restrict__ P, const float* __restrict__ vin)
{
    __shared__ __align__(16) float xl[BC * ICH * D_IN];   // 2 KB
    __shared__ float wsum[2][4][BC];                      // 256 B (ii-dbuf)

    const int t  = threadIdx.x;
    const int ic = blockIdx.x & (NIC - 1);   // 0..255 (blk%8==ic%8: XCD swz)
    const int bc = blockIdx.x >> 8;          // 0..7
    const int b0 = bc * BC;
    const int i0 = ic * ICH;
    const int eq = t & 3;          // e quarter (4 e's)
    const int bh = (t >> 2) & 1;   // b half (4 b's each)
    const int n  = t >> 3;         // capsule 0..31
    const int w  = t >> 6;         // wave 0..3

    if (t < 128) {
        const int row = t >> 4, f = (t & 15) * 4;
        *(float4*)&xl[row * (ICH * D_IN) + f] =
            *(const float4*)&x[((size_t)(b0 + row) * I_TOT + i0) * D_IN + f];
    }

    float4 vr[4];
    #pragma unroll
    for (int q = 0; q < 4; ++q)
        vr[q] = *(const float4*)&vin[(size_t)(b0 + bh * 4 + q) * OD + n * EV + eq * 4];
    __syncthreads();

    float4 sacc[4];
    #pragma unroll
    for (int q = 0; q < 4; ++q) sacc[q] = make_float4(0.f, 0.f, 0.f, 0.f);

    const float* Wt = &W[(size_t)i0 * 4096 + n * 128 + eq * 4];

    // unroll 1 is load-bearing (spill law: R3/R4 hoist -> 1.1 GB scratch).
    // iir = (ii + bc) & 7 de-phases the 8 bc-siblings of this ic.
    #pragma unroll 1
    for (int ii = 0; ii < ICH; ++ii) {
        const int iir = (ii + bc) & 7;
        float4 wr[8];
        #pragma unroll
        for (int d = 0; d < 8; ++d)
            wr[d] = *(const float4*)&Wt[iir * 4096 + d * 16];

        float4 u[4];
        #pragma unroll
        for (int q = 0; q < 4; ++q) {
            const int bl = bh * 4 + q;
            float4 xa = *(float4*)&xl[bl * (ICH * D_IN) + iir * 8];
            float4 xb = *(float4*)&xl[bl * (ICH * D_IN) + iir * 8 + 4];
            float4 uu = make_float4(0.f, 0.f, 0.f, 0.f);
            fma4(uu, xa.x, wr[0]); fma4(uu, xa.y, wr[1]);
            fma4(uu, xa.z, wr[2]); fma4(uu, xa.w, wr[3]);
            fma4(uu, xb.x, wr[4]); fma4(uu, xb.y, wr[5]);
            fma4(uu, xb.z, wr[6]); fma4(uu, xb.w, wr[7]);
            u[q] = uu;
        }

        float a[4];
        #pragma unroll
        for (int q = 0; q < 4; ++q) {
            float ap = u[q].x * vr[q].x + u[q].y * vr[q].y
                     + u[q].z * vr[q].z + u[q].w * vr[q].w;
            ap += __shfl_xor(ap, 1, 64);
            ap += __shfl_xor(ap, 2, 64);
            a[q] = ap;
        }
        float e[4], p[4];
        #pragma unroll
        for (int q = 0; q < 4; ++q) {
            e[q] = __expf(a[q]);
            float pp = e[q];
            pp += __shfl_xor(pp, 8, 64);
            pp += __shfl_xor(pp, 16, 64);
            pp += __shfl_xor(pp, 32, 64);
            p[q] = pp;
        }
        if (eq == 0) {
            #pragma unroll
            for (int q = 0; q < 4; ++q)
                wsum[ii & 1][w][bh * 4 + q] = p[q];
        }
        __syncthreads();
        #pragma unroll
        for (int q = 0; q < 4; ++q) {
            const int bl = bh * 4 + q;
            float s = wsum[ii & 1][0][bl] + wsum[ii & 1][1][bl]
                    + wsum[ii & 1][2][bl] + wsum[ii & 1][3][bl];
            float c = e[q] / s;
            fma4(sacc[q], c, u[q]);
        }
    }

    #pragma unroll
    for (int q = 0; q < 4; ++q)
        *(float4*)&P[((size_t)ic * B_TOT + b0 + bh * 4 + q) * OD + n * EV + eq * 4] = sacc[q];
}

// ---- reduce P over 256 i-chunks, squash, write v (or out). 512 blocks
// (b x 8 o-slices), exclusive writes. If addsrc != null, dst += addsrc
// (produces vs = v0 + v1 for pass 2 via dot linearity).
__global__ __launch_bounds__(256, 4)
void reduce_sq(const float* __restrict__ P, float* __restrict__ dst,
               const float* __restrict__ addsrc, float pre)
{
    __shared__ float red[256];
    const int b   = blockIdx.x >> 3;
    const int oq  = blockIdx.x & 7;
    const int t   = threadIdx.x;
    const int o   = oq * 64 + (t & 63);
    const int icq = t >> 6;                       // 0..3
    const size_t stride = (size_t)B_TOT * OD;

    float acc = 0.f;
    size_t base = ((size_t)(icq * 64) * B_TOT + b) * OD + o;
    #pragma unroll 8
    for (int k = 0; k < 64; ++k) acc += P[base + (size_t)k * stride];
    red[t] = acc;
    __syncthreads();

    if (t < 64) {
        float v = (red[t] + red[t + 64] + red[t + 128] + red[t + 192]) * pre;
        float q2 = v * v;
        q2 += __shfl_xor(q2, 1, 64);
        q2 += __shfl_xor(q2, 2, 64);
        q2 += __shfl_xor(q2, 4, 64);
        q2 += __shfl_xor(q2, 8, 64);
        float sc = q2 / ((1.0f + q2) * sqrtf(q2));
        float outv = v * sc;
        if (addsrc) outv += addsrc[(size_t)b * OD + o];
        dst[(size_t)b * OD + o] = outv;
    }
}

extern "C" void kernel_launch(void* const* d_in, const int* in_sizes, int n_in,
                              void* d_out, int out_size, void* d_ws, size_t ws_size,
                              hipStream_t stream) {
    const float* x = (const float*)d_in[0];
    const float* W = (const float*)d_in[1];
    float* out = (float*)d_out;

    char* ws = (char*)d_ws;
    float* P  = (float*)ws;                               // 32 MB
    float* v0 = (float*)(ws + (size_t)32 * 1024 * 1024);  // 128 KB each
    float* vs = v0 + S_ELEMS;                             // v0 + v1

    dim3 g0(NBC * NC), b0k(512);     // 256 blocks x 512 thr
    dim3 r1g(NBC * NIC), rb(256);    // 2048 blocks
    dim3 sg(B_TOT * 8), sb(256);     // 512 blocks

    // iter 0: v0 = squash((1/32) sum_i u) — one dispatch, no P
    route0d<<<g0, b0k, 0, stream>>>(x, W, v0);
    // iter 1: c = softmax(u . v0)
    route1<<<r1g, rb, 0, stream>>>(x, W, P, v0);
    // vs = v0 + v1  (iter-2 logits: u.v0 + u.v1 = u.(v0+v1))
    reduce_sq<<<sg, sb, 0, stream>>>(P, vs, v0, 1.0f);
    // iter 2: c = softmax(u . vs); final
    route1<<<r1g, rb, 0, stream>>>(x, W, P, vs);
    reduce_sq<<<sg, sb, 0, stream>>>(P, out, nullptr, 1.0f);
}

// Round 18
// 185.419 us; speedup vs baseline: 1.2354x; 1.2354x over previous
//
#include <hip/hip_runtime.h>
#include <math.h>

// CapsLayer dynamic routing, MI355X fp32.
// x: [64, 2048, 8]  W: [2048, 32, 8, 16]  out: [64, 32, 16]
// Never materialize u_hat (256 MB); recompute per routing pass.
// R20: halve P for the softmax passes. R19 (cooperative fusion) never
// launched (absmax = max|ref| = memset-zero out; cooperative launch rejected
// in harness capture) — abandoned per tripwire. R17 ledger: route1 43.7x2
// immovable; reduce_sq ~11us each is BW-bound on the 32 MB P. Lever:
// route1 accumulates ICH1=16 i's per block (sacc absorbs 2x before the P
// write) -> P(passes 1/2) = 16 MB: reduce1/2 ~6us, route1 P-write traffic
// halved, grid 1024 = 4 blk/CU (matches measured residency). Inner body
// byte-identical (live set unchanged; trip 16 doesn't unroll — R0/R2 ran
// ICH=16 at 36 VGPR clean). route0 (BC0=16 GEMM, never in top-5) + its
// KPT=64 reduce unchanged.
// Spill law (R3/R4/R6/R8/R16): #pragma unroll 1 on every i-loop.
// Tripwires: route1 <= 47us (else revert R17), FETCH <= 80 MB, VGPR <= 64,
// absmax 0.00098.

#define B_TOT 64
#define I_TOT 2048
#define D_IN  8
#define NC    32
#define EV    16
#define OD    (NC*EV)      // 512 outputs per b
#define BC    8            // batch rows per block (softmax passes)
#define NBC   (B_TOT/BC)   // 8 b-chunks
#define BC0   16           // batch rows per block (pass-0 GEMM)
#define NBC0  (B_TOT/BC0)  // 4 b-chunks
#define ICH0  8            // i's per block, pass 0
#define NIC0  (I_TOT/ICH0) // 256 i-chunks, pass 0
#define ICH1  16           // i's per block, passes 1/2
#define NIC1  (I_TOT/ICH1) // 128 i-chunks, passes 1/2
#define S_ELEMS (B_TOT*OD) // 32768 floats = 128 KB per v-slice

__device__ __forceinline__ void fma4(float4& acc, float a, const float4& w) {
    acc.x = fmaf(a, w.x, acc.x);
    acc.y = fmaf(a, w.y, acc.y);
    acc.z = fmaf(a, w.z, acc.z);
    acc.w = fmaf(a, w.w, acc.w);
}

// ---- pass 0: c uniform. GEMM form, BC0=16 (R16/R17 proven). ----
__global__ __launch_bounds__(256, 4)
void route0(const float* __restrict__ x, const float* __restrict__ W,
            float* __restrict__ P)
{
    __shared__ __align__(16) float xl[BC0 * ICH0 * D_IN];  // 4 KB

    const int t  = threadIdx.x;
    const int ic = blockIdx.x & (NIC0 - 1);  // 0..255 (blk%8==ic%8: XCD swz)
    const int bc = blockIdx.x >> 8;          // 0..3
    const int b0 = bc * BC0;
    const int i0 = ic * ICH0;
    const int eq = t & 3;
    const int bh = (t >> 2) & 1;
    const int n  = t >> 3;

    {
        const int row = t >> 4, f = (t & 15) * 4;
        *(float4*)&xl[row * (ICH0 * D_IN) + f] =
            *(const float4*)&x[((size_t)(b0 + row) * I_TOT + i0) * D_IN + f];
    }
    __syncthreads();

    float4 sacc[8];
    #pragma unroll
    for (int q = 0; q < 8; ++q) sacc[q] = make_float4(0.f, 0.f, 0.f, 0.f);

    const float* Wt = &W[(size_t)i0 * 4096 + n * 128 + eq * 4];

    // unroll 1 is load-bearing (spill law); iir de-phases the 4 bc-siblings
    #pragma unroll 1
    for (int ii = 0; ii < ICH0; ++ii) {
        const int iir = (ii + bc * 2) & 7;
        float4 wr[8];
        #pragma unroll
        for (int d = 0; d < 8; ++d)
            wr[d] = *(const float4*)&Wt[iir * 4096 + d * 16];

        #pragma unroll
        for (int q = 0; q < 8; ++q) {
            const int bl = bh * 8 + q;
            float4 xa = *(float4*)&xl[bl * (ICH0 * D_IN) + iir * 8];
            float4 xb = *(float4*)&xl[bl * (ICH0 * D_IN) + iir * 8 + 4];
            fma4(sacc[q], xa.x, wr[0]); fma4(sacc[q], xa.y, wr[1]);
            fma4(sacc[q], xa.z, wr[2]); fma4(sacc[q], xa.w, wr[3]);
            fma4(sacc[q], xb.x, wr[4]); fma4(sacc[q], xb.y, wr[5]);
            fma4(sacc[q], xb.z, wr[6]); fma4(sacc[q], xb.w, wr[7]);
        }
    }

    #pragma unroll
    for (int q = 0; q < 8; ++q)
        *(float4*)&P[((size_t)ic * B_TOT + b0 + bh * 8 + q) * OD + n * EV + eq * 4] = sacc[q];
}

// ---- passes 1/2: c = softmax_n(u . vin). R13/R17's proven body with
// ICH1=16 (sacc accumulates 16 i's -> P halves to 16 MB). Grid 1024.
// (iter 2 uses vin = v0+v1: dot is linear, so no logit carry needed)
__global__ __launch_bounds__(256, 4)
void route1(const float* __restrict__ x, const float* __restrict__ W,
            float* __restrict__ P, const float* __restrict__ vin)
{
    __shared__ __align__(16) float xl[BC * ICH1 * D_IN];  // 4 KB
    __shared__ float wsum[2][4][BC];                      // 256 B (ii-dbuf)

    const int t  = threadIdx.x;
    const int ic = blockIdx.x & (NIC1 - 1);  // 0..127 (blk%8==ic%8: XCD swz)
    const int bc = blockIdx.x >> 7;          // 0..7
    const int b0 = bc * BC;
    const int i0 = ic * ICH1;
    const int eq = t & 3;          // e quarter (4 e's)
    const int bh = (t >> 2) & 1;   // b half (4 b's each)
    const int n  = t >> 3;         // capsule 0..31
    const int w  = t >> 6;         // wave 0..3

    {   // stage x[b0..b0+7][i0..i0+15][0..7] = 256 float4, one per thread
        const int row = t >> 5, f = (t & 31) * 4;
        *(float4*)&xl[row * (ICH1 * D_IN) + f] =
            *(const float4*)&x[((size_t)(b0 + row) * I_TOT + i0) * D_IN + f];
    }

    float4 vr[4];
    #pragma unroll
    for (int q = 0; q < 4; ++q)
        vr[q] = *(const float4*)&vin[(size_t)(b0 + bh * 4 + q) * OD + n * EV + eq * 4];
    __syncthreads();

    float4 sacc[4];
    #pragma unroll
    for (int q = 0; q < 4; ++q) sacc[q] = make_float4(0.f, 0.f, 0.f, 0.f);

    const float* Wt = &W[(size_t)i0 * 4096 + n * 128 + eq * 4];

    // unroll 1 is load-bearing (spill law: R3/R4 hoist -> 1.1 GB scratch).
    // iir = (ii + bc*2) & 15 de-phases the 8 bc-siblings of this ic.
    #pragma unroll 1
    for (int ii = 0; ii < ICH1; ++ii) {
        const int iir = (ii + bc * 2) & 15;
        float4 wr[8];
        #pragma unroll
        for (int d = 0; d < 8; ++d)
            wr[d] = *(const float4*)&Wt[iir * 4096 + d * 16];

        float4 u[4];
        #pragma unroll
        for (int q = 0; q < 4; ++q) {
            const int bl = bh * 4 + q;
            float4 xa = *(float4*)&xl[bl * (ICH1 * D_IN) + iir * 8];
            float4 xb = *(float4*)&xl[bl * (ICH1 * D_IN) + iir * 8 + 4];
            float4 uu = make_float4(0.f, 0.f, 0.f, 0.f);
            fma4(uu, xa.x, wr[0]); fma4(uu, xa.y, wr[1]);
            fma4(uu, xa.z, wr[2]); fma4(uu, xa.w, wr[3]);
            fma4(uu, xb.x, wr[4]); fma4(uu, xb.y, wr[5]);
            fma4(uu, xb.z, wr[6]); fma4(uu, xb.w, wr[7]);
            u[q] = uu;
        }

        float a[4];
        #pragma unroll
        for (int q = 0; q < 4; ++q) {
            float ap = u[q].x * vr[q].x + u[q].y * vr[q].y
                     + u[q].z * vr[q].z + u[q].w * vr[q].w;
            ap += __shfl_xor(ap, 1, 64);
            ap += __shfl_xor(ap, 2, 64);
            a[q] = ap;
        }
        float e[4], p[4];
        #pragma unroll
        for (int q = 0; q < 4; ++q) {
            e[q] = __expf(a[q]);
            float pp = e[q];
            pp += __shfl_xor(pp, 8, 64);
            pp += __shfl_xor(pp, 16, 64);
            pp += __shfl_xor(pp, 32, 64);
            p[q] = pp;
        }
        if (eq == 0) {
            #pragma unroll
            for (int q = 0; q < 4; ++q)
                wsum[ii & 1][w][bh * 4 + q] = p[q];
        }
        __syncthreads();
        #pragma unroll
        for (int q = 0; q < 4; ++q) {
            const int bl = bh * 4 + q;
            float s = wsum[ii & 1][0][bl] + wsum[ii & 1][1][bl]
                    + wsum[ii & 1][2][bl] + wsum[ii & 1][3][bl];
            float c = e[q] / s;
            fma4(sacc[q], c, u[q]);
        }
    }

    #pragma unroll
    for (int q = 0; q < 4; ++q)
        *(float4*)&P[((size_t)ic * B_TOT + b0 + bh * 4 + q) * OD + n * EV + eq * 4] = sacc[q];
}

// ---- reduce P over NICK i-chunks (KPT = NICK/4 per thread), squash, write
// v (or out). 512 blocks (b x 8 o-slices), exclusive writes. If addsrc !=
// null, dst += addsrc (produces vs = v0 + v1 for pass 2 via dot linearity).
template <int KPT>
__global__ __launch_bounds__(256, 4)
void reduce_sq(const float* __restrict__ P, float* __restrict__ dst,
               const float* __restrict__ addsrc, float pre)
{
    __shared__ float red[256];
    const int b   = blockIdx.x >> 3;
    const int oq  = blockIdx.x & 7;
    const int t   = threadIdx.x;
    const int o   = oq * 64 + (t & 63);
    const int icq = t >> 6;                       // 0..3
    const size_t stride = (size_t)B_TOT * OD;

    float acc = 0.f;
    size_t base = ((size_t)(icq * KPT) * B_TOT + b) * OD + o;
    #pragma unroll 8
    for (int k = 0; k < KPT; ++k) acc += P[base + (size_t)k * stride];
    red[t] = acc;
    __syncthreads();

    if (t < 64) {
        float v = (red[t] + red[t + 64] + red[t + 128] + red[t + 192]) * pre;
        float q2 = v * v;
        q2 += __shfl_xor(q2, 1, 64);
        q2 += __shfl_xor(q2, 2, 64);
        q2 += __shfl_xor(q2, 4, 64);
        q2 += __shfl_xor(q2, 8, 64);
        float sc = q2 / ((1.0f + q2) * sqrtf(q2));
        float outv = v * sc;
        if (addsrc) outv += addsrc[(size_t)b * OD + o];
        dst[(size_t)b * OD + o] = outv;
    }
}

extern "C" void kernel_launch(void* const* d_in, const int* in_sizes, int n_in,
                              void* d_out, int out_size, void* d_ws, size_t ws_size,
                              hipStream_t stream) {
    const float* x = (const float*)d_in[0];
    const float* W = (const float*)d_in[1];
    float* out = (float*)d_out;

    char* ws = (char*)d_ws;
    float* P  = (float*)ws;                               // 32 MB (pass0) / 16 MB (1,2)
    float* v0 = (float*)(ws + (size_t)32 * 1024 * 1024);  // 128 KB each
    float* vs = v0 + S_ELEMS;                             // v0 + v1

    dim3 r0g(NBC0 * NIC0), r1g(NBC * NIC1), rb(256);  // 1024 / 1024 blocks
    dim3 sg(B_TOT * 8), sb(256);                      // 512 blocks

    // iter 0: uniform c (1/32 applied as pre in the v0 squash)
    route0<<<r0g, rb, 0, stream>>>(x, W, P);
    reduce_sq<64><<<sg, sb, 0, stream>>>(P, v0, nullptr, 1.0f / 32.0f);
    // iter 1: c = softmax(u . v0)
    route1<<<r1g, rb, 0, stream>>>(x, W, P, v0);
    // vs = v0 + v1  (iter-2 logits: u.v0 + u.v1 = u.(v0+v1))
    reduce_sq<32><<<sg, sb, 0, stream>>>(P, vs, v0, 1.0f);
    // iter 2: c = softmax(u . vs); final
    route1<<<r1g, rb, 0, stream>>>(x, W, P, vs);
    reduce_sq<32><<<sg, sb, 0, stream>>>(P, out, nullptr, 1.0f);
}